// Round 7
// baseline (599.114 us; speedup 1.0000x reference)
//
#include <hip/hip_runtime.h>
#include <hip/hip_bf16.h>
#include <math.h>

// ---------------- problem constants ----------------
#define OC     256
#define IC     128
#define HW     56
#define NB     64
#define KK     1152          // IC*9
#define HP     58            // padded spatial
#define PIX    (HW*HW)       // 3136
#define XPAD_ELEMS ((long)NB*HP*HP*IC)   // 27,557,888
#define A_ELEMS    (OC*KK)               // 294,912

typedef __attribute__((ext_vector_type(8))) short          bf16x8;
typedef __attribute__((ext_vector_type(8))) unsigned short u16x8;
typedef __attribute__((ext_vector_type(4))) float          f32x4;

__device__ __forceinline__ void async_load16(const void* g, void* l) {
    __builtin_amdgcn_global_load_lds(
        (const __attribute__((address_space(1))) void*)g,
        (__attribute__((address_space(3))) void*)l, 16, 0, 0);
}

// bf16 RNE convert
__device__ __forceinline__ unsigned short f2bf(float f) {
    unsigned int u = __float_as_uint(f);
    return (unsigned short)((u + 0x7fffu + ((u >> 16) & 1u)) >> 16);
}
__device__ __forceinline__ float bf2f(unsigned short b) {
    return __uint_as_float(((unsigned int)b) << 16);
}

// XOR-swizzled LDS element offset (2-way bank aliasing only — free, m136)
__device__ __forceinline__ int lds_off(int row, int q) {
    return row * 32 + (((q ^ (row >> 1)) & 3) << 3);
}

// ---------------- kernel 1: weights + BN constants ----------------
__global__ __launch_bounds__(256) void prep_weights(
        const float* __restrict__ phase, const float* __restrict__ gamma,
        const float* __restrict__ beta,  const float* __restrict__ rmean,
        const float* __restrict__ rvar,
        __hip_bfloat16* __restrict__ ah, __hip_bfloat16* __restrict__ al,
        float* __restrict__ scale, float* __restrict__ bias) {
    int g = blockIdx.x * 256 + threadIdx.x;      // 0 .. 294911
    int oc = g / KK;
    int kk = g - oc * KK;
    int kpos = kk >> 7;          // kh*3+kw
    int ic   = kk & 127;
    int j    = ic * 9 + kpos;    // original flat k = ic*9 + kh*3 + kw
    int pidx = (((oc >> 3) * 144 + (j >> 3)) * 8 + (oc & 7)) * 8 + (j & 7);
    double phi = (double)phase[pidx];
    double c   = cos(phi);
    const double a = 0.987, r = 0.99;
    double num = a*a - 2.0*a*r*c + r*r;
    double den = 1.0 - 2.0*a*r*c + (a*r)*(a*r);
    float t = (float)(num / den);
    unsigned short hb = f2bf(t);
    float hf = bf2f(hb);
    ((unsigned short*)ah)[g] = hb;
    ((unsigned short*)al)[g] = f2bf(t - hf);
    if (g < OC) {
        float inv = gamma[g] / sqrtf(rvar[g] + 1e-5f);
        scale[g] = inv;
        bias[g]  = beta[g] - rmean[g] * inv;
    }
}

// ---------------- kernel 2: pad + transpose + bf16 hi/lo split ----------------
// tile layout [w][ic] stride 132 -> phase-2 reads are aligned b128, conflict-free
__global__ __launch_bounds__(256) void prep_x(
        const float* __restrict__ x,
        __hip_bfloat16* __restrict__ xh, __hip_bfloat16* __restrict__ xl) {
    int hp  = blockIdx.x;    // 0..57
    int img = blockIdx.y;    // 0..63
    __shared__ float tile[HW * 132];   // [w][ic], stride 132 (29.6 KB)
    int t = threadIdx.x;
    bool border = (hp == 0) || (hp == HP - 1);
    if (!border) {
        int h = hp - 1;
        const float* src = x + (long)img * IC * PIX + (long)h * HW;
#pragma unroll
        for (int i = 0; i < 7; ++i) {            // 1792 float4 loads
            int idx = i * 256 + t;
            int ic  = idx / 14;
            int w4  = (idx - ic * 14) * 4;
            float4 v = *(const float4*)&src[(long)ic * PIX + w4];
            tile[(w4 + 0) * 132 + ic] = v.x;
            tile[(w4 + 1) * 132 + ic] = v.y;
            tile[(w4 + 2) * 132 + ic] = v.z;
            tile[(w4 + 3) * 132 + ic] = v.w;
        }
    }
    __syncthreads();
    long base = ((long)(img * HP + hp)) * HP * IC;
#pragma unroll
    for (int i = 0; i < 4; ++i) {                // 58*16 = 928 vec-tasks
        int v = i * 256 + t;
        if (v < 928) {
            int icg = v & 15;                    // 8 ic per task
            int wp  = v >> 4;                    // 0..57
            bool inw = !border && wp >= 1 && wp <= HW;
            float4 f0 = {0.f, 0.f, 0.f, 0.f}, f1 = {0.f, 0.f, 0.f, 0.f};
            if (inw) {
                const float* row = &tile[(wp - 1) * 132 + icg * 8];
                f0 = *(const float4*)row;        // aligned b128
                f1 = *(const float4*)(row + 4);
            }
            float fs[8] = {f0.x, f0.y, f0.z, f0.w, f1.x, f1.y, f1.z, f1.w};
            u16x8 hv, lv;
#pragma unroll
            for (int j = 0; j < 8; ++j) {
                unsigned short hb = f2bf(fs[j]);
                hv[j] = hb;
                lv[j] = f2bf(fs[j] - bf2f(hb));
            }
            long o = base + wp * IC + icg * 8;
            *(u16x8*)&((unsigned short*)xh)[o] = hv;
            *(u16x8*)&((unsigned short*)xl)[o] = lv;
        }
    }
}

// ---------------- kernel 3: implicit GEMM conv + BN + ReLU6 ----------------
// LDS dbuf + register frag dbuf + XCD swizzle (R6) + INTERLEAVED schedule:
// per half-iter: 4x [4 ds_read(next frags) ; 12 MFMA(current)] pinned with
// sched_group_barrier so LDS pipe and MFMA pipe co-issue (kill the convoy).
__global__ __launch_bounds__(256, 2) void conv_gemm(
        const __hip_bfloat16* __restrict__ ah, const __hip_bfloat16* __restrict__ al,
        const __hip_bfloat16* __restrict__ xh, const __hip_bfloat16* __restrict__ xl,
        const float* __restrict__ scale, const float* __restrict__ bias,
        float* __restrict__ out) {
    __shared__ __hip_bfloat16 sAh0[4096], sAl0[4096], sBh0[4096], sBl0[4096];
    __shared__ __hip_bfloat16 sAh1[4096], sAl1[4096], sBh1[4096], sBl1[4096];

    // XCD-aware swizzle: XCD x gets imgs [x*8, x*8+8) -> xh/xl L2-resident per XCD
    int b   = blockIdx.x;
    int xcd = b & 7;
    int idx = b >> 3;            // 0..399 per XCD
    int img = xcd * 8 + idx / 50;
    int rem = idx % 50;
    int mt  = rem >> 1;          // 0..24  pixel tile
    int ot  = rem & 1;           // oc tile

    int t    = threadIdx.x;
    int lane = t & 63;
    int wave = t >> 6;
    int wm   = wave & 1;     // oc half (64)
    int wn   = wave >> 1;    // pixel half (64)

    int row0 = t >> 2;
    int col0 = (((t & 3) ^ ((t >> 3) & 3))) << 3;

    const __hip_bfloat16* pah0 = ah + (long)(ot * 128 + row0) * KK + col0;
    const __hip_bfloat16* pah1 = pah0 + (long)64 * KK;
    const __hip_bfloat16* pal0 = al + (long)(ot * 128 + row0) * KK + col0;
    const __hip_bfloat16* pal1 = pal0 + (long)64 * KK;

    int m0 = mt * 128 + row0;      if (m0 > PIX - 1) m0 = PIX - 1;
    int m1 = mt * 128 + row0 + 64; if (m1 > PIX - 1) m1 = PIX - 1;
    int h0 = m0 / HW, w0 = m0 - h0 * HW;
    int h1 = m1 / HW, w1 = m1 - h1 * HW;
    const __hip_bfloat16* pxh0 = xh + (long)((img * HP + h0) * HP + w0) * IC + col0;
    const __hip_bfloat16* pxh1 = xh + (long)((img * HP + h1) * HP + w1) * IC + col0;
    const __hip_bfloat16* pxl0 = xl + (long)((img * HP + h0) * HP + w0) * IC + col0;
    const __hip_bfloat16* pxl1 = xl + (long)((img * HP + h1) * HP + w1) * IC + col0;

    int ar[4], br[4];
#pragma unroll
    for (int f = 0; f < 4; ++f) {
        ar[f] = lds_off(wm * 64 + f * 16 + (lane & 15), lane >> 4);
        br[f] = lds_off(wn * 64 + f * 16 + (lane & 15), lane >> 4);
    }

    f32x4 acc[4][4];
#pragma unroll
    for (int i = 0; i < 4; ++i)
#pragma unroll
        for (int jj = 0; jj < 4; ++jj) acc[i][jj] = (f32x4){0.f, 0.f, 0.f, 0.f};

    bf16x8 aH0[4], aL0[4], bH0[4], bL0[4];
    bf16x8 aH1[4], aL1[4], bH1[4], bL1[4];

#define ISSUE(ci, SAH, SAL, SBH, SBL)                                          \
    {                                                                           \
        int bs = 32 * (ci) + ((ci) >= 12 ? 7040 : 0) + ((ci) >= 24 ? 7040 : 0); \
        long a0 = (long)(ci) * 32;                                              \
        async_load16(pah0 + a0, &SAH[t * 8]);                                   \
        async_load16(pah1 + a0, &SAH[2048 + t * 8]);                            \
        async_load16(pal0 + a0, &SAL[t * 8]);                                   \
        async_load16(pal1 + a0, &SAL[2048 + t * 8]);                            \
        async_load16(pxh0 + bs, &SBH[t * 8]);                                   \
        async_load16(pxh1 + bs, &SBH[2048 + t * 8]);                            \
        async_load16(pxl0 + bs, &SBL[t * 8]);                                   \
        async_load16(pxl1 + bs, &SBL[2048 + t * 8]);                            \
    }

// interleaved: read frag f of NEXT chunk (into RN regs from SN LDS), then the
// 12 MFMAs of row f of CURRENT chunk (RC regs). sched_group_barrier pins the
// 2 vmem / 4 ds / 12 mfma rhythm per f.
#define HALF_ITER(AHN, ALN, BHN, BLN, SAHN, SALN, SBHN, SBLN,                   \
                  AHC, ALC, BHC, BLC)                                           \
    {                                                                           \
        _Pragma("unroll")                                                       \
        for (int f = 0; f < 4; ++f) {                                           \
            AHN[f] = *(const bf16x8*)&SAHN[ar[f]];                              \
            ALN[f] = *(const bf16x8*)&SALN[ar[f]];                              \
            BHN[f] = *(const bf16x8*)&SBHN[br[f]];                              \
            BLN[f] = *(const bf16x8*)&SBLN[br[f]];                              \
            _Pragma("unroll")                                                   \
            for (int fn = 0; fn < 4; ++fn) {                                    \
                acc[f][fn] = __builtin_amdgcn_mfma_f32_16x16x32_bf16(ALC[f], BHC[fn], acc[f][fn], 0, 0, 0); \
                acc[f][fn] = __builtin_amdgcn_mfma_f32_16x16x32_bf16(AHC[f], BLC[fn], acc[f][fn], 0, 0, 0); \
                acc[f][fn] = __builtin_amdgcn_mfma_f32_16x16x32_bf16(AHC[f], BHC[fn], acc[f][fn], 0, 0, 0); \
            }                                                                   \
            __builtin_amdgcn_sched_group_barrier(0x020, 2, 0);  /* 2 VMEM   */  \
            __builtin_amdgcn_sched_group_barrier(0x100, 4, 0);  /* 4 DS rd  */  \
            __builtin_amdgcn_sched_group_barrier(0x008, 12, 0); /* 12 MFMA  */  \
        }                                                                       \
    }

#define MFMAS(AH, AL, BH, BL)                                                   \
    {                                                                           \
        _Pragma("unroll")                                                       \
        for (int fm = 0; fm < 4; ++fm)                                          \
            _Pragma("unroll")                                                   \
            for (int fn = 0; fn < 4; ++fn) {                                    \
                acc[fm][fn] = __builtin_amdgcn_mfma_f32_16x16x32_bf16(AL[fm], BH[fn], acc[fm][fn], 0, 0, 0); \
                acc[fm][fn] = __builtin_amdgcn_mfma_f32_16x16x32_bf16(AH[fm], BL[fn], acc[fm][fn], 0, 0, 0); \
                acc[fm][fn] = __builtin_amdgcn_mfma_f32_16x16x32_bf16(AH[fm], BH[fn], acc[fm][fn], 0, 0, 0); \
            }                                                                   \
    }

    // prologue: stage 0, drain, stage 1, read frags(0)
    ISSUE(0, sAh0, sAl0, sBh0, sBl0);
    __syncthreads();
    ISSUE(1, sAh1, sAl1, sBh1, sBl1);
#pragma unroll
    for (int f = 0; f < 4; ++f) {
        aH0[f] = *(const bf16x8*)&sAh0[ar[f]];
        aL0[f] = *(const bf16x8*)&sAl0[ar[f]];
        bH0[f] = *(const bf16x8*)&sBh0[br[f]];
        bL0[f] = *(const bf16x8*)&sBl0[br[f]];
    }

#pragma unroll 1
    for (int cc = 0; cc < 17; ++cc) {
        int c = cc * 2;
        // half A: consume c (set0), read frags(c+1) (set1), stage c+2 -> buf0
        __syncthreads();                               // drains staging(c+1) + reads of set0 src
        ISSUE(c + 2, sAh0, sAl0, sBh0, sBl0);
        HALF_ITER(aH1, aL1, bH1, bL1, sAh1, sAl1, sBh1, sBl1,
                  aH0, aL0, bH0, bL0);
        // half B: consume c+1 (set1), read frags(c+2) (set0), stage c+3 -> buf1
        __syncthreads();
        ISSUE(c + 3, sAh1, sAl1, sBh1, sBl1);
        HALF_ITER(aH0, aL0, bH0, bL0, sAh0, sAl0, sBh0, sBl0,
                  aH1, aL1, bH1, bL1);
    }
    // tail: chunks 34, 35 (staged in buf0/buf1; set0 holds frags(34))
    __syncthreads();
    HALF_ITER(aH1, aL1, bH1, bL1, sAh1, sAl1, sBh1, sBl1,
              aH0, aL0, bH0, bL0);                     // consume 34, read 35
    MFMAS(aH1, aL1, bH1, bL1);                         // consume 35
#undef ISSUE
#undef HALF_ITER
#undef MFMAS

    // epilogue: BN (eval) + ReLU6, store fp32
    int pixc = mt * 128 + wn * 64 + (lane & 15);
    int occ0 = ot * 128 + wm * 64 + ((lane >> 4) << 2);
#pragma unroll
    for (int fm = 0; fm < 4; ++fm) {
#pragma unroll
        for (int r = 0; r < 4; ++r) {
            int oc = occ0 + fm * 16 + r;
            float sc = scale[oc], bi = bias[oc];
            long obase = ((long)(img * OC + oc)) * PIX;
#pragma unroll
            for (int fn = 0; fn < 4; ++fn) {
                int pix = pixc + fn * 16;
                if (pix < PIX) {
                    float v = acc[fm][fn][r] * sc + bi;
                    v = fminf(fmaxf(v, 0.f), 6.f);
                    out[obase + pix] = v;
                }
            }
        }
    }
}

// ---------------- launch ----------------
extern "C" void kernel_launch(void* const* d_in, const int* in_sizes, int n_in,
                              void* d_out, int out_size, void* d_ws, size_t ws_size,
                              hipStream_t stream) {
    const float* x     = (const float*)d_in[0];
    const float* phase = (const float*)d_in[1];
    const float* gamma = (const float*)d_in[2];
    const float* beta  = (const float*)d_in[3];
    const float* rmean = (const float*)d_in[4];
    const float* rvar  = (const float*)d_in[5];
    float* out = (float*)d_out;

    __hip_bfloat16* xh = (__hip_bfloat16*)d_ws;
    __hip_bfloat16* xl = xh + XPAD_ELEMS;
    __hip_bfloat16* ah = xl + XPAD_ELEMS;
    __hip_bfloat16* al = ah + A_ELEMS;
    float* scale = (float*)(al + A_ELEMS);
    float* bias  = scale + OC;

    prep_weights<<<A_ELEMS / 256, 256, 0, stream>>>(phase, gamma, beta, rmean, rvar,
                                                    ah, al, scale, bias);
    prep_x<<<dim3(HP, NB), 256, 0, stream>>>(x, xh, xl);
    conv_gemm<<<NB * 50, 256, 0, stream>>>(ah, al, xh, xl, scale, bias, out);
}